// Round 18
// baseline (242.305 us; speedup 1.0000x reference)
//
#include <hip/hip_runtime.h>
#include <hip/hip_bf16.h>

typedef __attribute__((ext_vector_type(8))) short short8;
typedef __attribute__((ext_vector_type(4))) float f32x4;

#define N_NODES 20000
#define N_EDGES 320000
#define NFEAT 512
#define NHID 1024
#define MBTOT 1252
#define SCAN_NB 79   // ceil(20000/256)

__device__ __forceinline__ float bf2f(unsigned short u) {
    union { unsigned int i; float f; } c; c.i = ((unsigned int)u) << 16; return c.f;
}
__device__ __forceinline__ unsigned short f2bf(float f) {
    union { float f; unsigned int i; } c; c.f = f;
    unsigned int x = c.i;
    return (unsigned short)((x + 0x7fffu + ((x >> 16) & 1u)) >> 16);
}

// ---------------- CSR build ----------------

__global__ void hist_kernel(const int* __restrict__ dst, int* __restrict__ deg, int E) {
    int e = blockIdx.x * 256 + threadIdx.x;
    if (e < E) atomicAdd(&deg[dst[e]], 1);
}

__global__ __launch_bounds__(256) void scan_a(const int* __restrict__ deg,
                                              int* __restrict__ rp,
                                              int* __restrict__ part, int n) {
    __shared__ int sd[256];
    int t = threadIdx.x;
    int i = blockIdx.x * 256 + t;
    int v = (i < n) ? deg[i] : 0;
    int acc = v;
    sd[t] = acc;
    __syncthreads();
    for (int off = 1; off < 256; off <<= 1) {
        int u = (t >= off) ? sd[t - off] : 0;
        __syncthreads();
        acc += u;
        sd[t] = acc;
        __syncthreads();
    }
    if (i < n) rp[i] = acc - v;
    if (t == 255) part[blockIdx.x] = acc;
}

__global__ __launch_bounds__(256) void scan_b(int* __restrict__ part, int nb) {
    __shared__ int sd[256];
    int t = threadIdx.x;
    int v = (t < nb) ? part[t] : 0;
    int acc = v;
    sd[t] = acc;
    __syncthreads();
    for (int off = 1; off < 256; off <<= 1) {
        int u = (t >= off) ? sd[t - off] : 0;
        __syncthreads();
        acc += u;
        sd[t] = acc;
        __syncthreads();
    }
    if (t < nb) part[t] = acc - v;
    if (t == 255) part[nb] = acc;
}

__global__ __launch_bounds__(256) void scan_c(int* __restrict__ rp, int* __restrict__ cursor,
                                              const int* __restrict__ part, int n, int nb) {
    int i = blockIdx.x * 256 + threadIdx.x;
    if (i < n) {
        int v = rp[i] + part[blockIdx.x];
        rp[i] = v;
        cursor[i] = v;
    }
    if (i == 0) rp[n] = part[nb];
}

// csr_ov packs (byte-offset = src*1024, val bits) into one int2
__global__ void fill_kernel(const int* __restrict__ src, const int* __restrict__ dst,
                            const float* __restrict__ vals, int* __restrict__ cursor,
                            int2* __restrict__ csr_ov, int E) {
    int e = blockIdx.x * 256 + threadIdx.x;
    if (e < E) {
        int d = dst[e];
        int pos = atomicAdd(&cursor[d], 1);
        csr_ov[pos] = make_int2(src[e] << 10, __float_as_int(vals[e]));
    }
}

// ------------- W transpose + bf16 + MFMA-fragment pack (both weights, one launch) -------------

__device__ __forceinline__ void transpose_body(const float* __restrict__ W,
                                               unsigned short* __restrict__ Bp,
                                               int K, int N, int bid) {
    __shared__ float tile[32][33];
    const int KT = K >> 5;
    int ntx = N >> 5;
    int k0 = (bid / ntx) << 5;
    int n0 = (bid % ntx) << 5;
    int tx = threadIdx.x & 31, ty = threadIdx.x >> 5;
#pragma unroll
    for (int i = 0; i < 32; i += 8)
        tile[ty + i][tx] = W[(size_t)(k0 + ty + i) * N + n0 + tx];
    __syncthreads();
#pragma unroll
    for (int i = 0; i < 32; i += 8) {
        int n = n0 + ty + i;
        int k = k0 + tx;
        int nb = n >> 4, rl = n & 15;
        int kb = k >> 5, kq = (k & 31) >> 3, j = k & 7;
        Bp[((((size_t)nb * KT + kb) * 64) + kq * 16 + rl) * 8 + j] = f2bf(tile[tx][ty + i]);
    }
}

__global__ __launch_bounds__(256) void transpose2_kernel(const float* __restrict__ W1,
                                                         unsigned short* __restrict__ w1p,
                                                         const float* __restrict__ W2,
                                                         unsigned short* __restrict__ w2p) {
    if (blockIdx.x < 512) transpose_body(W1, w1p, NFEAT, NHID, blockIdx.x);
    else                  transpose_body(W2, w2p, NHID, NFEAT, blockIdx.x - 512);
}

// ------------- merged prep: x->bf16 cvt (blocks 0..4999) + mask pack (5000..14999) -------------

__global__ __launch_bounds__(256) void prep_kernel(const float* __restrict__ x,
                                                   unsigned short* __restrict__ xb,
                                                   const float* __restrict__ u,
                                                   unsigned int* __restrict__ mask) {
    __shared__ unsigned char nib[256];
    int b = blockIdx.x;
    int t = threadIdx.x;
    if (b < 5000) {
        int i = b * 256 + t;
        f32x4 v0 = ((const f32x4*)x)[i * 2];
        f32x4 v1 = ((const f32x4*)x)[i * 2 + 1];
        short8 o;
#pragma unroll
        for (int j = 0; j < 4; ++j) {
            o[j]     = (short)f2bf(v0[j]);
            o[4 + j] = (short)f2bf(v1[j]);
        }
        ((short8*)xb)[i] = o;
    } else {
        size_t base = (size_t)(b - 5000) * 2048;
        f32x4 v0 = ((const f32x4*)(u + base))[t * 2];
        f32x4 v1 = ((const f32x4*)(u + base))[t * 2 + 1];
        unsigned n = 0;
#pragma unroll
        for (int j = 0; j < 4; ++j) {
            n |= (v0[j] > 0.5f ? 1u : 0u) << j;
            n |= (v1[j] > 0.5f ? 1u : 0u) << (4 + j);
        }
        nib[t] = (unsigned char)n;
        __syncthreads();
        if (t < 64) {
            unsigned w = (unsigned)nib[t * 4] | ((unsigned)nib[t * 4 + 1] << 8) |
                         ((unsigned)nib[t * 4 + 2] << 16) | ((unsigned)nib[t * 4 + 3] << 24);
            mask[base / 32 + t] = w;
        }
    }
}

// ------------- XCD-pinned chunked aggregation: csr 2-ahead + gather 1-ahead -------------
// Each 8-lane group owns one dst node; lane s handles feats c*64+s*8 (16B gathers).
// Batch b's 8 gathers are issued one batch ahead so they overlap batch b-1's
// fma+cvt consume phase. Remainder (<8 edges) uses group-uniform loads.

template <typename OutFn>
__device__ __forceinline__ void agg_core(const char* xc, const int2* __restrict__ csr_ov,
                                         int e0, int e1, int glane, int s,
                                         f32x4& a0, f32x4& a1) {
    const int nfull = (e1 - e0) >> 3;

    int offX = 0; float valX = 0.f;
    int offY = 0; float valY = 0.f;
    short8 w[8];

    if (nfull > 0) {
        int2 t = csr_ov[e0 + s]; offX = t.x; valX = __int_as_float(t.y);
        if (nfull > 1) { int2 t2 = csr_ov[e0 + 8 + s]; offY = t2.x; valY = __int_as_float(t2.y); }
#pragma unroll
        for (int i = 0; i < 8; ++i)
            w[i] = *(const short8*)(xc + __shfl(offX, glane + i));
    }

    for (int b = 0; b < nfull; ++b) {
        int offZ = 0; float valZ = 0.f;
        if (b + 2 < nfull) {
            int2 t = csr_ov[e0 + (b + 2) * 8 + s]; offZ = t.x; valZ = __int_as_float(t.y);
        }
        short8 w2[8];
        if (b + 1 < nfull) {
#pragma unroll
            for (int i = 0; i < 8; ++i)
                w2[i] = *(const short8*)(xc + __shfl(offY, glane + i));
        }
        // consume batch b
#pragma unroll
        for (int i = 0; i < 8; ++i) {
            float val = __shfl(valX, glane + i);
#pragma unroll
            for (int j = 0; j < 4; ++j) {
                a0[j] += val * bf2f((unsigned short)w[i][j]);
                a1[j] += val * bf2f((unsigned short)w[i][4 + j]);
            }
        }
        offX = offY; valX = valY;
        offY = offZ; valY = valZ;
#pragma unroll
        for (int i = 0; i < 8; ++i) w[i] = w2[i];
    }
    // remainder: group-uniform loads (<= 7 edges)
    for (int e = e0 + nfull * 8; e < e1; ++e) {
        int2 t = csr_ov[e];
        float val = __int_as_float(t.y);
        short8 ww = *(const short8*)(xc + t.x);
#pragma unroll
        for (int j = 0; j < 4; ++j) {
            a0[j] += val * bf2f((unsigned short)ww[j]);
            a1[j] += val * bf2f((unsigned short)ww[4 + j]);
        }
    }
}

__global__ __launch_bounds__(256) void agg1_kernel(const unsigned short* __restrict__ xbf,
                                                   const int2* __restrict__ csr_ov,
                                                   const int* __restrict__ row_ptr,
                                                   unsigned short* __restrict__ A1p) {
    const int c = blockIdx.x & 7;                  // chunk == XCD
    const int dbase = (blockIdx.x >> 3) * 32;
    const int wid = threadIdx.x >> 6;
    const int lane = threadIdx.x & 63;
    const int g = lane >> 3;
    const int s = lane & 7;
    const int d = dbase + wid * 8 + g;
    const int e0 = row_ptr[d], e1 = row_ptr[d + 1];
    const char* xc = (const char*)xbf + (c * 64 + s * 8) * 2;

    f32x4 a0 = {0.f, 0.f, 0.f, 0.f}, a1 = {0.f, 0.f, 0.f, 0.f};
    agg_core<int>(xc, csr_ov, e0, e1, g * 8, s, a0, a1);

    short8 o;
#pragma unroll
    for (int j = 0; j < 4; ++j) {
        o[j]     = (short)f2bf(a0[j]);
        o[4 + j] = (short)f2bf(a1[j]);
    }
    size_t idx = ((((size_t)(d >> 4) * (NFEAT / 32) + (c * 2 + (s >> 2))) * 64) +
                  (s & 3) * 16 + (d & 15)) * 8;
    *(short8*)&A1p[idx] = o;
}

__global__ __launch_bounds__(256) void agg2_kernel(const unsigned short* __restrict__ s2,
                                                   const int2* __restrict__ csr_ov,
                                                   const int* __restrict__ row_ptr,
                                                   const float* __restrict__ b2,
                                                   float* __restrict__ out) {
    const int c = blockIdx.x & 7;
    const int dbase = (blockIdx.x >> 3) * 32;
    const int wid = threadIdx.x >> 6;
    const int lane = threadIdx.x & 63;
    const int g = lane >> 3;
    const int s = lane & 7;
    const int d = dbase + wid * 8 + g;
    const int e0 = row_ptr[d], e1 = row_ptr[d + 1];
    const int fb = c * 64 + s * 8;
    const char* xc = (const char*)s2 + fb * 2;

    f32x4 a0 = *(const f32x4*)&b2[fb];
    f32x4 a1 = *(const f32x4*)&b2[fb + 4];
    agg_core<int>(xc, csr_ov, e0, e1, g * 8, s, a0, a1);

    *(f32x4*)&out[(size_t)d * NFEAT + fb]     = a0;
    *(f32x4*)&out[(size_t)d * NFEAT + fb + 4] = a1;
}

// ------------- fragment-packed register GEMM, 32x64 wave tile, 2-deep pipeline -------------
// EPI==1: bias+relu (LDS write) + dropout via coalesced mask word (read), packed out.
// EPI==0: LDS-transposed row-major output (4x16B stores/lane instead of 32x2B).

template <int EPI, int KT, int NW>
__global__ __launch_bounds__(256, 4) void gemm_pk(
    const unsigned short* __restrict__ Ap,
    const unsigned short* __restrict__ Bp,
    unsigned short* __restrict__ C,
    int M,
    const float* __restrict__ bias,
    const unsigned int* __restrict__ umask) {
    constexpr int N = NW * 64;
    constexpr int MI_MAX = 625;    // 20000/32 exactly

    const int nwg = gridDim.x;
    const int bid = blockIdx.x;
    const int q = nwg >> 3, r = nwg & 7;
    const int xcd = bid & 7, pos = bid >> 3;
    const int swz = (xcd < r ? xcd * (q + 1) : r * (q + 1) + (xcd - r) * q) + pos;

    const int wid = threadIdx.x >> 6;
    const int lane = threadIdx.x & 63;
    const int rl = lane & 15;
    const int kq = lane >> 4;

    constexpr int NT2 = NW / 2;
    const int bm = swz / NT2;
    const int bn = swz % NT2;
    int mi = bm * 2 + (wid >> 1); if (mi >= MI_MAX) mi = MI_MAX - 1;
    const int ni = bn * 2 + (wid & 1);

    const unsigned short* ab = Ap + (size_t)(mi * 2) * KT * 512 + lane * 8;
    const unsigned short* bb = Bp + (size_t)(ni * 4) * KT * 512 + lane * 8;

    f32x4 acc[2][4] = {};
    short8 aX[2], bX[4], aY[2], bY[4];

#pragma unroll
    for (int m = 0; m < 2; ++m) aX[m] = *(const short8*)(ab + (size_t)m * KT * 512);
#pragma unroll
    for (int n = 0; n < 4; ++n) bX[n] = *(const short8*)(bb + (size_t)n * KT * 512);

#pragma unroll 1
    for (int kb = 0; kb < KT; kb += 2) {
#pragma unroll
        for (int m = 0; m < 2; ++m)
            aY[m] = *(const short8*)(ab + ((size_t)m * KT + kb + 1) * 512);
#pragma unroll
        for (int n = 0; n < 4; ++n)
            bY[n] = *(const short8*)(bb + ((size_t)n * KT + kb + 1) * 512);
#pragma unroll
        for (int m = 0; m < 2; ++m)
#pragma unroll
            for (int n = 0; n < 4; ++n)
                acc[m][n] = __builtin_amdgcn_mfma_f32_16x16x32_bf16(aX[m], bX[n], acc[m][n], 0, 0, 0);
        if (kb + 2 < KT) {
#pragma unroll
            for (int m = 0; m < 2; ++m)
                aX[m] = *(const short8*)(ab + ((size_t)m * KT + kb + 2) * 512);
#pragma unroll
            for (int n = 0; n < 4; ++n)
                bX[n] = *(const short8*)(bb + ((size_t)n * KT + kb + 2) * 512);
        }
#pragma unroll
        for (int m = 0; m < 2; ++m)
#pragma unroll
            for (int n = 0; n < 4; ++n)
                acc[m][n] = __builtin_amdgcn_mfma_f32_16x16x32_bf16(aY[m], bY[n], acc[m][n], 0, 0, 0);
    }

    // epilogue: wave-private bf16 LDS transpose; padded row stride 40 ushorts
    __shared__ unsigned short ltr[4][32][40];
#pragma unroll
    for (int n2 = 0; n2 < 2; ++n2) {
#pragma unroll
        for (int m = 0; m < 2; ++m) {
#pragma unroll
            for (int nn = 0; nn < 2; ++nn) {
                int n = n2 * 2 + nn;
                float bv = (EPI == 1) ? bias[ni * 64 + n * 16 + rl] : 0.f;
#pragma unroll
                for (int j = 0; j < 4; ++j) {
                    float v = acc[m][n][j];
                    if (EPI == 1) {
                        v += bv;
                        v = v > 0.f ? v : 0.f;
                    }
                    ltr[wid][m * 16 + kq * 4 + j][nn * 16 + rl] = f2bf(v);
                }
            }
        }
        __builtin_amdgcn_s_waitcnt(0);  // wave-private LDS: writes visible
#pragma unroll
        for (int m2 = 0; m2 < 2; ++m2) {
            int row = m2 * 16 + rl;
            int gr = mi * 32 + row;
            short8 u = *(const short8*)&ltr[wid][row][kq * 8];
            if constexpr (EPI == 1) {
                constexpr int KT2 = N / 32;
                unsigned w = umask[(size_t)gr * (N >> 5) + (ni * 2 + n2)];
                short8 o;
#pragma unroll
                for (int j = 0; j < 4; ++j) {
                    o[j]     = ((w >> (kq * 8 + j)) & 1u)
                               ? (short)f2bf(bf2f((unsigned short)u[j]) * 2.0f) : (short)0;
                    o[4 + j] = ((w >> (kq * 8 + 4 + j)) & 1u)
                               ? (short)f2bf(bf2f((unsigned short)u[4 + j]) * 2.0f) : (short)0;
                }
                int mbg = mi * 2 + m2;
                size_t dst = (((size_t)mbg * KT2 + (ni * 2 + n2)) * 64 + lane) * 8;
                *(short8*)&C[dst] = o;
            } else {
                *(short8*)&C[(size_t)gr * N + ni * 64 + n2 * 32 + kq * 8] = u;
            }
        }
        __builtin_amdgcn_s_waitcnt(0);  // reads done before next n2 overwrites
    }
}

// ---------------- launch ----------------

extern "C" void kernel_launch(void* const* d_in, const int* in_sizes, int n_in,
                              void* d_out, int out_size, void* d_ws, size_t ws_size,
                              hipStream_t stream) {
    const float* x        = (const float*)d_in[0];
    const float* W1       = (const float*)d_in[1];
    const float* b1       = (const float*)d_in[2];
    const float* W2       = (const float*)d_in[3];
    const float* b2       = (const float*)d_in[4];
    const float* adj_vals = (const float*)d_in[5];
    const float* u_drop   = (const float*)d_in[6];
    const int*   src      = (const int*)d_in[7];
    const int*   dst      = (const int*)d_in[8];
    float* out = (float*)d_out;

    char* p = (char*)d_ws;
    auto take = [&](size_t bytes) {
        char* q = p;
        p += (bytes + 255) & ~(size_t)255;
        return q;
    };
    int* deg        = (int*)take((size_t)N_NODES * 4);
    int* row_ptr    = (int*)take((size_t)(N_NODES + 1) * 4);
    int* cursor     = (int*)take((size_t)N_NODES * 4);
    int* part       = (int*)take((size_t)(SCAN_NB + 1) * 4);
    int2* csr_ov    = (int2*)take((size_t)N_EDGES * 8);
    unsigned short* w1p   = (unsigned short*)take((size_t)NFEAT * NHID * 2);
    unsigned short* w2p   = (unsigned short*)take((size_t)NFEAT * NHID * 2);
    unsigned short* xbf   = (unsigned short*)take((size_t)N_NODES * NFEAT * 2);
    unsigned short* a1p   = (unsigned short*)take((size_t)MBTOT * (NFEAT / 32) * 1024);
    unsigned short* a2p   = (unsigned short*)take((size_t)MBTOT * (NHID / 32) * 1024);
    unsigned short* s2buf = (unsigned short*)take((size_t)N_NODES * NFEAT * 2);
    unsigned int* umask   = (unsigned int*)take((size_t)N_NODES * (NHID / 32) * 4);

    hipMemsetAsync(deg, 0, (size_t)N_NODES * 4, stream);
    hist_kernel<<<(N_EDGES + 255) / 256, 256, 0, stream>>>(dst, deg, N_EDGES);
    scan_a<<<SCAN_NB, 256, 0, stream>>>(deg, row_ptr, part, N_NODES);
    scan_b<<<1, 256, 0, stream>>>(part, SCAN_NB);
    scan_c<<<SCAN_NB, 256, 0, stream>>>(row_ptr, cursor, part, N_NODES, SCAN_NB);
    fill_kernel<<<(N_EDGES + 255) / 256, 256, 0, stream>>>(src, dst, adj_vals, cursor,
                                                           csr_ov, N_EDGES);
    transpose2_kernel<<<1024, 256, 0, stream>>>(W1, w1p, W2, w2p);
    prep_kernel<<<15000, 256, 0, stream>>>(x, xbf, u_drop, umask);

    agg1_kernel<<<8 * 625, 256, 0, stream>>>(xbf, csr_ov, row_ptr, a1p);

    gemm_pk<1, NFEAT / 32, NHID / 64><<<313 * (NHID / 128), 256, 0, stream>>>(
        a1p, w1p, a2p, N_NODES, b1, umask);
    gemm_pk<0, NHID / 32, NFEAT / 64><<<313 * (NFEAT / 128), 256, 0, stream>>>(
        a2p, w2p, s2buf, N_NODES, nullptr, nullptr);

    agg2_kernel<<<8 * 625, 256, 0, stream>>>(s2buf, csr_ov, row_ptr, b2, out);
}

// Round 19
// 230.697 us; speedup vs baseline: 1.0503x; 1.0503x over previous
//
#include <hip/hip_runtime.h>
#include <hip/hip_bf16.h>

typedef __attribute__((ext_vector_type(8))) short short8;
typedef __attribute__((ext_vector_type(4))) float f32x4;

#define N_NODES 20000
#define N_EDGES 320000
#define NFEAT 512
#define NHID 1024
#define MBTOT 1252
#define SCAN_NB 79   // ceil(20000/256)

__device__ __forceinline__ float bf2f(unsigned short u) {
    union { unsigned int i; float f; } c; c.i = ((unsigned int)u) << 16; return c.f;
}
__device__ __forceinline__ unsigned short f2bf(float f) {
    union { float f; unsigned int i; } c; c.f = f;
    unsigned int x = c.i;
    return (unsigned short)((x + 0x7fffu + ((x >> 16) & 1u)) >> 16);
}

// ---------------- CSR build ----------------

__global__ void hist_kernel(const int* __restrict__ dst, int* __restrict__ deg, int E) {
    int e = blockIdx.x * 256 + threadIdx.x;
    if (e < E) atomicAdd(&deg[dst[e]], 1);
}

__global__ __launch_bounds__(256) void scan_a(const int* __restrict__ deg,
                                              int* __restrict__ rp,
                                              int* __restrict__ part, int n) {
    __shared__ int sd[256];
    int t = threadIdx.x;
    int i = blockIdx.x * 256 + t;
    int v = (i < n) ? deg[i] : 0;
    int acc = v;
    sd[t] = acc;
    __syncthreads();
    for (int off = 1; off < 256; off <<= 1) {
        int u = (t >= off) ? sd[t - off] : 0;
        __syncthreads();
        acc += u;
        sd[t] = acc;
        __syncthreads();
    }
    if (i < n) rp[i] = acc - v;
    if (t == 255) part[blockIdx.x] = acc;
}

__global__ __launch_bounds__(256) void scan_b(int* __restrict__ part, int nb) {
    __shared__ int sd[256];
    int t = threadIdx.x;
    int v = (t < nb) ? part[t] : 0;
    int acc = v;
    sd[t] = acc;
    __syncthreads();
    for (int off = 1; off < 256; off <<= 1) {
        int u = (t >= off) ? sd[t - off] : 0;
        __syncthreads();
        acc += u;
        sd[t] = acc;
        __syncthreads();
    }
    if (t < nb) part[t] = acc - v;
    if (t == 255) part[nb] = acc;
}

__global__ __launch_bounds__(256) void scan_c(int* __restrict__ rp, int* __restrict__ cursor,
                                              const int* __restrict__ part, int n, int nb) {
    int i = blockIdx.x * 256 + threadIdx.x;
    if (i < n) {
        int v = rp[i] + part[blockIdx.x];
        rp[i] = v;
        cursor[i] = v;
    }
    if (i == 0) rp[n] = part[nb];
}

// csr_ov packs (byte-offset = src*1024, val bits) into one int2
__global__ void fill_kernel(const int* __restrict__ src, const int* __restrict__ dst,
                            const float* __restrict__ vals, int* __restrict__ cursor,
                            int2* __restrict__ csr_ov, int E) {
    int e = blockIdx.x * 256 + threadIdx.x;
    if (e < E) {
        int d = dst[e];
        int pos = atomicAdd(&cursor[d], 1);
        csr_ov[pos] = make_int2(src[e] << 10, __float_as_int(vals[e]));
    }
}

// ------------- W transpose + bf16 + MFMA-fragment pack (both weights, one launch) -------------

__device__ __forceinline__ void transpose_body(const float* __restrict__ W,
                                               unsigned short* __restrict__ Bp,
                                               int K, int N, int bid) {
    __shared__ float tile[32][33];
    const int KT = K >> 5;
    int ntx = N >> 5;
    int k0 = (bid / ntx) << 5;
    int n0 = (bid % ntx) << 5;
    int tx = threadIdx.x & 31, ty = threadIdx.x >> 5;
#pragma unroll
    for (int i = 0; i < 32; i += 8)
        tile[ty + i][tx] = W[(size_t)(k0 + ty + i) * N + n0 + tx];
    __syncthreads();
#pragma unroll
    for (int i = 0; i < 32; i += 8) {
        int n = n0 + ty + i;
        int k = k0 + tx;
        int nb = n >> 4, rl = n & 15;
        int kb = k >> 5, kq = (k & 31) >> 3, j = k & 7;
        Bp[((((size_t)nb * KT + kb) * 64) + kq * 16 + rl) * 8 + j] = f2bf(tile[tx][ty + i]);
    }
}

__global__ __launch_bounds__(256) void transpose2_kernel(const float* __restrict__ W1,
                                                         unsigned short* __restrict__ w1p,
                                                         const float* __restrict__ W2,
                                                         unsigned short* __restrict__ w2p) {
    if (blockIdx.x < 512) transpose_body(W1, w1p, NFEAT, NHID, blockIdx.x);
    else                  transpose_body(W2, w2p, NHID, NFEAT, blockIdx.x - 512);
}

// ------------- merged prep: x->bf16 cvt (blocks 0..4999) + mask pack (5000..14999) -------------

__global__ __launch_bounds__(256) void prep_kernel(const float* __restrict__ x,
                                                   unsigned short* __restrict__ xb,
                                                   const float* __restrict__ u,
                                                   unsigned int* __restrict__ mask) {
    __shared__ unsigned char nib[256];
    int b = blockIdx.x;
    int t = threadIdx.x;
    if (b < 5000) {
        int i = b * 256 + t;
        f32x4 v0 = ((const f32x4*)x)[i * 2];
        f32x4 v1 = ((const f32x4*)x)[i * 2 + 1];
        short8 o;
#pragma unroll
        for (int j = 0; j < 4; ++j) {
            o[j]     = (short)f2bf(v0[j]);
            o[4 + j] = (short)f2bf(v1[j]);
        }
        ((short8*)xb)[i] = o;
    } else {
        size_t base = (size_t)(b - 5000) * 2048;
        f32x4 v0 = ((const f32x4*)(u + base))[t * 2];
        f32x4 v1 = ((const f32x4*)(u + base))[t * 2 + 1];
        unsigned n = 0;
#pragma unroll
        for (int j = 0; j < 4; ++j) {
            n |= (v0[j] > 0.5f ? 1u : 0u) << j;
            n |= (v1[j] > 0.5f ? 1u : 0u) << (4 + j);
        }
        nib[t] = (unsigned char)n;
        __syncthreads();
        if (t < 64) {
            unsigned w = (unsigned)nib[t * 4] | ((unsigned)nib[t * 4 + 1] << 8) |
                         ((unsigned)nib[t * 4 + 2] << 16) | ((unsigned)nib[t * 4 + 3] << 24);
            mask[base / 32 + t] = w;
        }
    }
}

// ------------- XCD-pinned chunked aggregation 1 (shfl + 2-deep csr pipeline) -------------

__global__ __launch_bounds__(256) void agg1_kernel(const unsigned short* __restrict__ xbf,
                                                   const int2* __restrict__ csr_ov,
                                                   const int* __restrict__ row_ptr,
                                                   unsigned short* __restrict__ A1p) {
    const int c = blockIdx.x & 7;                  // chunk == XCD
    const int dbase = (blockIdx.x >> 3) * 32;
    const int wid = threadIdx.x >> 6;
    const int lane = threadIdx.x & 63;
    const int g = lane >> 3;
    const int s = lane & 7;
    const int d = dbase + wid * 8 + g;
    const int e0 = row_ptr[d], e1 = row_ptr[d + 1];
    const char* xc = (const char*)xbf + (c * 64 + s * 8) * 2;
    const int glane = g * 8;

    f32x4 a0 = {0.f, 0.f, 0.f, 0.f}, a1 = {0.f, 0.f, 0.f, 0.f};

    int offX = 0; float valX = 0.f;
    if (e0 + s < e1) { int2 t = csr_ov[e0 + s]; offX = t.x; valX = __int_as_float(t.y); }

    for (int eb = e0; eb < e1; eb += 8) {
        int offY = 0; float valY = 0.f;
        if (eb + 8 + s < e1) { int2 t = csr_ov[eb + 8 + s]; offY = t.x; valY = __int_as_float(t.y); }
        int cnt = e1 - eb; if (cnt > 8) cnt = 8;
        if (cnt == 8) {
            short8 w[8];
#pragma unroll
            for (int i = 0; i < 8; ++i)
                w[i] = *(const short8*)(xc + __shfl(offX, glane + i));
#pragma unroll
            for (int i = 0; i < 8; ++i) {
                float val = __shfl(valX, glane + i);
#pragma unroll
                for (int j = 0; j < 4; ++j) {
                    a0[j] += val * bf2f((unsigned short)w[i][j]);
                    a1[j] += val * bf2f((unsigned short)w[i][4 + j]);
                }
            }
        } else {
            for (int i = 0; i < cnt; ++i) {
                int off = __shfl(offX, glane + i);
                float val = __shfl(valX, glane + i);
                short8 w = *(const short8*)(xc + off);
#pragma unroll
                for (int j = 0; j < 4; ++j) {
                    a0[j] += val * bf2f((unsigned short)w[j]);
                    a1[j] += val * bf2f((unsigned short)w[4 + j]);
                }
            }
        }
        offX = offY; valX = valY;
    }
    short8 o;
#pragma unroll
    for (int j = 0; j < 4; ++j) {
        o[j]     = (short)f2bf(a0[j]);
        o[4 + j] = (short)f2bf(a1[j]);
    }
    size_t idx = ((((size_t)(d >> 4) * (NFEAT / 32) + (c * 2 + (s >> 2))) * 64) +
                  (s & 3) * 16 + (d & 15)) * 8;
    *(short8*)&A1p[idx] = o;
}

// ------------- XCD-pinned chunked aggregation 2 (shfl + 2-deep csr pipeline) -------------

__global__ __launch_bounds__(256) void agg2_kernel(const unsigned short* __restrict__ s2,
                                                   const int2* __restrict__ csr_ov,
                                                   const int* __restrict__ row_ptr,
                                                   const float* __restrict__ b2,
                                                   float* __restrict__ out) {
    const int c = blockIdx.x & 7;
    const int dbase = (blockIdx.x >> 3) * 32;
    const int wid = threadIdx.x >> 6;
    const int lane = threadIdx.x & 63;
    const int g = lane >> 3;
    const int s = lane & 7;
    const int d = dbase + wid * 8 + g;
    const int e0 = row_ptr[d], e1 = row_ptr[d + 1];
    const int fb = c * 64 + s * 8;
    const char* xc = (const char*)s2 + fb * 2;
    const int glane = g * 8;

    f32x4 a0 = *(const f32x4*)&b2[fb];
    f32x4 a1 = *(const f32x4*)&b2[fb + 4];

    int offX = 0; float valX = 0.f;
    if (e0 + s < e1) { int2 t = csr_ov[e0 + s]; offX = t.x; valX = __int_as_float(t.y); }

    for (int eb = e0; eb < e1; eb += 8) {
        int offY = 0; float valY = 0.f;
        if (eb + 8 + s < e1) { int2 t = csr_ov[eb + 8 + s]; offY = t.x; valY = __int_as_float(t.y); }
        int cnt = e1 - eb; if (cnt > 8) cnt = 8;
        if (cnt == 8) {
            short8 w[8];
#pragma unroll
            for (int i = 0; i < 8; ++i)
                w[i] = *(const short8*)(xc + __shfl(offX, glane + i));
#pragma unroll
            for (int i = 0; i < 8; ++i) {
                float val = __shfl(valX, glane + i);
#pragma unroll
                for (int j = 0; j < 4; ++j) {
                    a0[j] += val * bf2f((unsigned short)w[i][j]);
                    a1[j] += val * bf2f((unsigned short)w[i][4 + j]);
                }
            }
        } else {
            for (int i = 0; i < cnt; ++i) {
                int off = __shfl(offX, glane + i);
                float val = __shfl(valX, glane + i);
                short8 w = *(const short8*)(xc + off);
#pragma unroll
                for (int j = 0; j < 4; ++j) {
                    a0[j] += val * bf2f((unsigned short)w[j]);
                    a1[j] += val * bf2f((unsigned short)w[4 + j]);
                }
            }
        }
        offX = offY; valX = valY;
    }
    *(f32x4*)&out[(size_t)d * NFEAT + fb]     = a0;
    *(f32x4*)&out[(size_t)d * NFEAT + fb + 4] = a1;
}

// ------------- fragment-packed register GEMM, 32x64 wave tile, 2-deep pipeline -------------
// EPI==1: bias+relu (LDS write) + dropout via coalesced mask word (read), packed out.
// EPI==0: LDS-transposed row-major output (4x16B stores/lane instead of 32x2B).

template <int EPI, int KT, int NW>
__global__ __launch_bounds__(256, 4) void gemm_pk(
    const unsigned short* __restrict__ Ap,
    const unsigned short* __restrict__ Bp,
    unsigned short* __restrict__ C,
    int M,
    const float* __restrict__ bias,
    const unsigned int* __restrict__ umask) {
    constexpr int N = NW * 64;
    constexpr int MI_MAX = 625;    // 20000/32 exactly

    const int nwg = gridDim.x;
    const int bid = blockIdx.x;
    const int q = nwg >> 3, r = nwg & 7;
    const int xcd = bid & 7, pos = bid >> 3;
    const int swz = (xcd < r ? xcd * (q + 1) : r * (q + 1) + (xcd - r) * q) + pos;

    const int wid = threadIdx.x >> 6;
    const int lane = threadIdx.x & 63;
    const int rl = lane & 15;
    const int kq = lane >> 4;

    constexpr int NT2 = NW / 2;
    const int bm = swz / NT2;
    const int bn = swz % NT2;
    int mi = bm * 2 + (wid >> 1); if (mi >= MI_MAX) mi = MI_MAX - 1;
    const int ni = bn * 2 + (wid & 1);

    const unsigned short* ab = Ap + (size_t)(mi * 2) * KT * 512 + lane * 8;
    const unsigned short* bb = Bp + (size_t)(ni * 4) * KT * 512 + lane * 8;

    f32x4 acc[2][4] = {};
    short8 aX[2], bX[4], aY[2], bY[4];

#pragma unroll
    for (int m = 0; m < 2; ++m) aX[m] = *(const short8*)(ab + (size_t)m * KT * 512);
#pragma unroll
    for (int n = 0; n < 4; ++n) bX[n] = *(const short8*)(bb + (size_t)n * KT * 512);

#pragma unroll 1
    for (int kb = 0; kb < KT; kb += 2) {
#pragma unroll
        for (int m = 0; m < 2; ++m)
            aY[m] = *(const short8*)(ab + ((size_t)m * KT + kb + 1) * 512);
#pragma unroll
        for (int n = 0; n < 4; ++n)
            bY[n] = *(const short8*)(bb + ((size_t)n * KT + kb + 1) * 512);
#pragma unroll
        for (int m = 0; m < 2; ++m)
#pragma unroll
            for (int n = 0; n < 4; ++n)
                acc[m][n] = __builtin_amdgcn_mfma_f32_16x16x32_bf16(aX[m], bX[n], acc[m][n], 0, 0, 0);
        if (kb + 2 < KT) {
#pragma unroll
            for (int m = 0; m < 2; ++m)
                aX[m] = *(const short8*)(ab + ((size_t)m * KT + kb + 2) * 512);
#pragma unroll
            for (int n = 0; n < 4; ++n)
                bX[n] = *(const short8*)(bb + ((size_t)n * KT + kb + 2) * 512);
        }
#pragma unroll
        for (int m = 0; m < 2; ++m)
#pragma unroll
            for (int n = 0; n < 4; ++n)
                acc[m][n] = __builtin_amdgcn_mfma_f32_16x16x32_bf16(aY[m], bY[n], acc[m][n], 0, 0, 0);
    }

    // epilogue: wave-private bf16 LDS transpose; padded row stride 40 ushorts
    __shared__ unsigned short ltr[4][32][40];
#pragma unroll
    for (int n2 = 0; n2 < 2; ++n2) {
#pragma unroll
        for (int m = 0; m < 2; ++m) {
#pragma unroll
            for (int nn = 0; nn < 2; ++nn) {
                int n = n2 * 2 + nn;
                float bv = (EPI == 1) ? bias[ni * 64 + n * 16 + rl] : 0.f;
#pragma unroll
                for (int j = 0; j < 4; ++j) {
                    float v = acc[m][n][j];
                    if (EPI == 1) {
                        v += bv;
                        v = v > 0.f ? v : 0.f;
                    }
                    ltr[wid][m * 16 + kq * 4 + j][nn * 16 + rl] = f2bf(v);
                }
            }
        }
        __builtin_amdgcn_s_waitcnt(0);  // wave-private LDS: writes visible
#pragma unroll
        for (int m2 = 0; m2 < 2; ++m2) {
            int row = m2 * 16 + rl;
            int gr = mi * 32 + row;
            short8 u = *(const short8*)&ltr[wid][row][kq * 8];
            if constexpr (EPI == 1) {
                constexpr int KT2 = N / 32;
                unsigned w = umask[(size_t)gr * (N >> 5) + (ni * 2 + n2)];
                short8 o;
#pragma unroll
                for (int j = 0; j < 4; ++j) {
                    o[j]     = ((w >> (kq * 8 + j)) & 1u)
                               ? (short)f2bf(bf2f((unsigned short)u[j]) * 2.0f) : (short)0;
                    o[4 + j] = ((w >> (kq * 8 + 4 + j)) & 1u)
                               ? (short)f2bf(bf2f((unsigned short)u[4 + j]) * 2.0f) : (short)0;
                }
                int mbg = mi * 2 + m2;
                size_t dst = (((size_t)mbg * KT2 + (ni * 2 + n2)) * 64 + lane) * 8;
                *(short8*)&C[dst] = o;
            } else {
                *(short8*)&C[(size_t)gr * N + ni * 64 + n2 * 32 + kq * 8] = u;
            }
        }
        __builtin_amdgcn_s_waitcnt(0);  // reads done before next n2 overwrites
    }
}

// ---------------- launch ----------------

extern "C" void kernel_launch(void* const* d_in, const int* in_sizes, int n_in,
                              void* d_out, int out_size, void* d_ws, size_t ws_size,
                              hipStream_t stream) {
    const float* x        = (const float*)d_in[0];
    const float* W1       = (const float*)d_in[1];
    const float* b1       = (const float*)d_in[2];
    const float* W2       = (const float*)d_in[3];
    const float* b2       = (const float*)d_in[4];
    const float* adj_vals = (const float*)d_in[5];
    const float* u_drop   = (const float*)d_in[6];
    const int*   src      = (const int*)d_in[7];
    const int*   dst      = (const int*)d_in[8];
    float* out = (float*)d_out;

    char* p = (char*)d_ws;
    auto take = [&](size_t bytes) {
        char* q = p;
        p += (bytes + 255) & ~(size_t)255;
        return q;
    };
    int* deg        = (int*)take((size_t)N_NODES * 4);
    int* row_ptr    = (int*)take((size_t)(N_NODES + 1) * 4);
    int* cursor     = (int*)take((size_t)N_NODES * 4);
    int* part       = (int*)take((size_t)(SCAN_NB + 1) * 4);
    int2* csr_ov    = (int2*)take((size_t)N_EDGES * 8);
    unsigned short* w1p   = (unsigned short*)take((size_t)NFEAT * NHID * 2);
    unsigned short* w2p   = (unsigned short*)take((size_t)NFEAT * NHID * 2);
    unsigned short* xbf   = (unsigned short*)take((size_t)N_NODES * NFEAT * 2);
    unsigned short* a1p   = (unsigned short*)take((size_t)MBTOT * (NFEAT / 32) * 1024);
    unsigned short* a2p   = (unsigned short*)take((size_t)MBTOT * (NHID / 32) * 1024);
    unsigned short* s2buf = (unsigned short*)take((size_t)N_NODES * NFEAT * 2);
    unsigned int* umask   = (unsigned int*)take((size_t)N_NODES * (NHID / 32) * 4);

    hipMemsetAsync(deg, 0, (size_t)N_NODES * 4, stream);
    hist_kernel<<<(N_EDGES + 255) / 256, 256, 0, stream>>>(dst, deg, N_EDGES);
    scan_a<<<SCAN_NB, 256, 0, stream>>>(deg, row_ptr, part, N_NODES);
    scan_b<<<1, 256, 0, stream>>>(part, SCAN_NB);
    scan_c<<<SCAN_NB, 256, 0, stream>>>(row_ptr, cursor, part, N_NODES, SCAN_NB);
    fill_kernel<<<(N_EDGES + 255) / 256, 256, 0, stream>>>(src, dst, adj_vals, cursor,
                                                           csr_ov, N_EDGES);
    transpose2_kernel<<<1024, 256, 0, stream>>>(W1, w1p, W2, w2p);
    prep_kernel<<<15000, 256, 0, stream>>>(x, xbf, u_drop, umask);

    agg1_kernel<<<8 * 625, 256, 0, stream>>>(xbf, csr_ov, row_ptr, a1p);

    gemm_pk<1, NFEAT / 32, NHID / 64><<<313 * (NHID / 128), 256, 0, stream>>>(
        a1p, w1p, a2p, N_NODES, b1, umask);
    gemm_pk<0, NHID / 32, NFEAT / 64><<<313 * (NFEAT / 128), 256, 0, stream>>>(
        a2p, w2p, s2buf, N_NODES, nullptr, nullptr);

    agg2_kernel<<<8 * 625, 256, 0, stream>>>(s2buf, csr_ov, row_ptr, b2, out);
}